// Round 4
// baseline (358.491 us; speedup 1.0000x reference)
//
#include <hip/hip_runtime.h>
#include <cmath>

#define NB 4
#define NN 8192
#define CH 32

typedef short short8 __attribute__((ext_vector_type(8)));
typedef float floatx4 __attribute__((ext_vector_type(4)));
typedef unsigned short ushort_t;

// ---------- helpers ----------
__device__ __forceinline__ unsigned short f2b(float f){
  unsigned u = __float_as_uint(f);
  u = u + 0x7FFFu + ((u >> 16) & 1u);   // RNE
  return (unsigned short)(u >> 16);
}
__device__ __forceinline__ float b2f(unsigned short h){
  return __uint_as_float(((unsigned)h) << 16);
}
__device__ __forceinline__ float gelu_f(float v){
  return 0.5f * v * (1.0f + erff(v * 0.70710678118654752440f));
}
// rep-index closed forms (t in [0,552), t = j*24+i)
__device__ __forceinline__ int repk(int t){   // -1 if t is not a representative
  int j = t / 24, i = t - j * 24;
  if(j == 0)  return (i <= 12) ? i : -1;
  if(j <= 11) return 13 + (j - 1) * 24 + i;
  return (i == 12) ? 277 + (j - 12) : -1;
}
__device__ __forceinline__ int partner(int t){
  int j = t / 24, i = t - j * 24;
  return ((23 - j) % 23) * 24 + ((24 - i) % 24);
}
__device__ __forceinline__ int repT(int k){   // inverse of repk over reps
  if(k < 13) return k;
  if(k < 277){ int m = k - 13; return (m / 24 + 1) * 24 + (m % 24); }
  return (k - 277 + 12) * 24 + 12;
}

// ---------- fused: spec_w reorder (blocks >=128) + minmax partials (blocks <128) ----------
__global__ __launch_bounds__(256) void k_pre(const float* __restrict__ spec,
    float2* __restrict__ wt, const float* __restrict__ x, float4* __restrict__ pmm)
{
  const int tid = threadIdx.x;
  if(blockIdx.x < 128){
    int g = blockIdx.x * 256 + tid;           // 32768 threads
    float a = x[(size_t)g * 2], b = x[(size_t)g * 2 + 1];
    float mn0 = a, mx0 = a, mn1 = b, mx1 = b;
    for(int off = 32; off > 0; off >>= 1){
      mn0 = fminf(mn0, __shfl_down(mn0, off));
      mx0 = fmaxf(mx0, __shfl_down(mx0, off));
      mn1 = fminf(mn1, __shfl_down(mn1, off));
      mx1 = fmaxf(mx1, __shfl_down(mx1, off));
    }
    __shared__ float4 wp[4];
    if((tid & 63) == 0) wp[tid >> 6] = make_float4(mn0, mn1, mx0, mx1);
    __syncthreads();
    if(tid == 0){
      float4 r = wp[0];
      for(int i2 = 1; i2 < 4; ++i2){
        float4 v = wp[i2];
        r.x = fminf(r.x, v.x); r.y = fminf(r.y, v.y);
        r.z = fmaxf(r.z, v.z); r.w = fmaxf(r.w, v.w);
      }
      pmm[blockIdx.x] = r;
    }
  } else {
    int g = (blockIdx.x - 128) * 256 + tid;   // 1,179,648
    int o  = g & 31;
    int i  = (g >> 5) & 31;
    int rest = g >> 10;
    int pq = rest % 144;
    int ls = rest / 144;                      // l*2+sel
    wt[g] = ((const float2*)spec)[(((size_t)(ls * 32 + i) * 32 + o) * 144 + pq)];
  }
}

// ---------- build V in MFMA-fragment layouts + fc0 ----------
// AF : forward A-operand.  [b][st=36][ng=256][q=4][srow=16][e=8] shorts
// VTF: inverse B-operand.  [b][n16=512][kk=18][q=4][n15=16][e=8] shorts
__global__ __launch_bounds__(256) void k_vbuild(const float* __restrict__ x,
    const float4* __restrict__ pmm, const float* __restrict__ fw,
    const float* __restrict__ fb, ushort_t* __restrict__ AF, ushort_t* __restrict__ VTF,
    float* __restrict__ h, ushort_t* __restrict__ hb)
{
  __shared__ ushort_t lds1[32 * 584];
  __shared__ float4 mmv;
  const int tid = threadIdx.x;
  if(tid < 64){
    float4 a = pmm[tid], c = pmm[tid + 64];
    float mn0 = fminf(a.x, c.x), mn1 = fminf(a.y, c.y);
    float mx0 = fmaxf(a.z, c.z), mx1 = fmaxf(a.w, c.w);
    for(int off = 32; off > 0; off >>= 1){
      mn0 = fminf(mn0, __shfl_down(mn0, off));
      mn1 = fminf(mn1, __shfl_down(mn1, off));
      mx0 = fmaxf(mx0, __shfl_down(mx0, off));
      mx1 = fmaxf(mx1, __shfl_down(mx1, off));
    }
    if(tid == 0) mmv = make_float4(mn0, mn1, mx0, mx1);
  }
  __syncthreads();
  const int nl = tid & 31, part = tid >> 5;
  const int b = blockIdx.x >> 8;
  const int nblk = blockIdx.x & 255;
  const int n = nblk * 32 + nl;
  float mn0 = mmv.x, mn1 = mmv.y, mx0 = mmv.z, mx1 = mmv.w;
  float x0 = x[(size_t)(b * NN + n) * 2]     - mn0;
  float x1 = x[(size_t)(b * NN + n) * 2 + 1] - mn1;
  float sp = x0 * (6.28f / (mx0 - mn0));
  float sq = x1 * (6.28f / (mx1 - mn1));
  float cx, sx, cy, sy;
  sincosf(sp, &sx, &cx);
  sincosf(sq, &sy, &cy);
  int j0 = part * 3;
  int j1 = (j0 + 3 < 23) ? j0 + 3 : 23;
  float ky0 = (j0 < 12) ? (float)j0 : (float)(j0 - 23);
  float cb, sb;
  sincosf(ky0 * sq, &sb, &cb);
  for(int j = j0; j < j1; ++j){
    float ca = 1.0f, sa = 0.0f;   // kx = 0
    #pragma unroll
    for(int i = 0; i < 24; ++i){
      float vr = ca * cb - sa * sb;        //  cos(kx*sp + ky*sq)
      float vi = -(sa * cb + ca * sb);     // -sin(kx*sp + ky*sq)
      int t = j * 24 + i;
      int k = repk(t);
      if(k >= 0){
        lds1[nl * 584 + k]       = f2b(vr);
        lds1[nl * 584 + 288 + k] = f2b(vi);
      }
      float cn = ca * cx - sa * sx;
      float sn = sa * cx + ca * sx;
      if(i == 11) sn = -sn;                // kx 11 -> -12 (conjugate)
      ca = cn; sa = sn;
    }
    float cbn = cb * cy - sb * sy;
    float sbn = sb * cy + cb * sy;
    cb = cbn; sb = sbn;
  }
  __syncthreads();
  // phase-1 emission: VTF (coalesced 16B/lane)
  #pragma unroll
  for(int r = 0; r < 9; ++r){
    int c = tid + 256 * r;                  // [0,2304)
    int t16 = c / 1152;
    int c2 = c - t16 * 1152;
    int kk = c2 >> 6;
    int rem = c2 & 63;
    int q = rem >> 4, n15 = rem & 15;
    short8 v = *(const short8*)(lds1 + (t16 * 16 + n15) * 584 + kk * 32 + q * 8);
    *(short8*)(VTF + ((size_t)((b * 512 + nblk * 2 + t16) * 18 + kk)) * 512
               + (q * 16 + n15) * 8) = v;
  }
  // phase-2 emission: AF via conjugate symmetry from LDS
  #pragma unroll
  for(int r = 0; r < 9; ++r){
    int c = tid + 256 * r;                  // [0,2304)
    int st = c >> 6;
    int rem = c & 63;
    int q = rem >> 4, srow = rem & 15;
    int sg = st * 16 + srow;                // [0,576)
    int s = (sg < 288) ? sg : sg - 288;
    int sinh_ = (sg >= 288);
    int p2 = s / 12, qq = s - p2 * 12;
    int t = p2 * 23 + qq;
    int k = repk(t);
    unsigned short flip = 0;
    if(k < 0){ k = repk(partner(t)); if(sinh_) flip = 0x8000; }
    int col = sinh_ ? 288 + k : k;
    ushort_t tmp[8];
    #pragma unroll
    for(int e = 0; e < 8; ++e)
      tmp[e] = lds1[(q * 8 + e) * 584 + col] ^ flip;
    *(short8*)(AF + ((size_t)((b * 36 + st) * 256 + nblk)) * 512
               + (q * 16 + srow) * 8) = *(short8*)tmp;
  }
  // fused fc0
  #pragma unroll
  for(int rr = 0; rr < 4; ++rr){
    int c2 = (tid >> 5) + rr * 8;
    float v = fb[c2] + x0 * fw[c2] + x1 * fw[32 + c2];
    size_t idx = (size_t)(b * CH + c2) * NN + n;
    h[idx] = v; hb[idx] = f2b(v);
  }
}

// ---------- forward transform (K-split 8, 2 s-tiles/block): xp[ks][b][576][32] ----------
__global__ __launch_bounds__(256) void k_fwd(const ushort_t* __restrict__ AF,
    const ushort_t* __restrict__ hb, float* __restrict__ xp)
{
  const int stp = blockIdx.x;      // 18 pairs
  const int ks = blockIdx.y;       // 8
  const int b  = blockIdx.z;
  const int w = threadIdx.x >> 6;
  const int lane = threadIdx.x & 63;
  const int row = lane & 15;
  const int q = lane >> 4;
  const int st0 = stp * 2;
  const size_t abase0 = ((size_t)(b * 36 + st0) * 256) * 512 + (q * 16 + row) * 8;
  const size_t abase1 = abase0 + (size_t)256 * 512;
  const size_t hb0 = (size_t)(b * CH + row) * NN;
  const size_t hb1 = hb0 + (size_t)16 * NN;
  floatx4 aA0 = {0.f,0.f,0.f,0.f}, aA1 = {0.f,0.f,0.f,0.f};
  floatx4 aB0 = {0.f,0.f,0.f,0.f}, aB1 = {0.f,0.f,0.f,0.f};
  #pragma unroll
  for(int kk = 0; kk < 8; ++kk){
    int g = ks * 32 + w * 8 + kk;
    short8 A0 = *(const short8*)(AF + abase0 + (size_t)g * 512);
    short8 A1 = *(const short8*)(AF + abase1 + (size_t)g * 512);
    int nn2 = g * 32 + q * 8;
    short8 B0 = *(const short8*)(hb + hb0 + nn2);
    short8 B1 = *(const short8*)(hb + hb1 + nn2);
    aA0 = __builtin_amdgcn_mfma_f32_16x16x32_bf16(A0, B0, aA0, 0, 0, 0);
    aA1 = __builtin_amdgcn_mfma_f32_16x16x32_bf16(A0, B1, aA1, 0, 0, 0);
    aB0 = __builtin_amdgcn_mfma_f32_16x16x32_bf16(A1, B0, aB0, 0, 0, 0);
    aB1 = __builtin_amdgcn_mfma_f32_16x16x32_bf16(A1, B1, aB1, 0, 0, 0);
  }
  __shared__ float red[4 * 512];
  const int e = threadIdx.x;
  #pragma unroll
  for(int r = 0; r < 4; ++r){
    int rrow = q * 4 + r;
    red[w * 512 + rrow * 32 + row]      = aA0[r];
    red[w * 512 + rrow * 32 + 16 + row] = aA1[r];
  }
  __syncthreads();
  {
    float v0 = red[e] + red[512 + e] + red[1024 + e] + red[1536 + e];
    float v1 = red[e + 256] + red[512 + e + 256] + red[1024 + e + 256] + red[1536 + e + 256];
    size_t base = ((size_t)(ks * NB + b) * 576 + st0 * 16) * 32;
    xp[base + e] = v0;
    xp[base + e + 256] = v1;
  }
  __syncthreads();
  #pragma unroll
  for(int r = 0; r < 4; ++r){
    int rrow = q * 4 + r;
    red[w * 512 + rrow * 32 + row]      = aB0[r];
    red[w * 512 + rrow * 32 + 16 + row] = aB1[r];
  }
  __syncthreads();
  {
    float v0 = red[e] + red[512 + e] + red[1024 + e] + red[1536 + e];
    float v1 = red[e + 256] + red[512 + e + 256] + red[1024 + e + 256] + red[1536 + e + 256];
    size_t base = ((size_t)(ks * NB + b) * 576 + (st0 + 1) * 16) * 32;
    xp[base + e] = v0;
    xp[base + e + 256] = v1;
  }
}

// ---------- fused mix + fold -> ghi/glo (wave per rep, 4 reps/block) ----------
__global__ __launch_bounds__(256) void k_mixg(const float* __restrict__ xp,
    const float2* __restrict__ wt, ushort_t* __restrict__ ghi, ushort_t* __restrict__ glo,
    int layer)
{
  const int w = threadIdx.x >> 6;
  const int lane = threadIdx.x & 63;
  const int k = blockIdx.x * 4 + w;    // 288 reps
  const int b = blockIdx.y;
  const int t = repT(k);
  const int j = t / 24, i = t - j * 24;
  const int u = partner(t);
  const bool unpaired = (i == 12) || (u == t);
  const int idxT = (t < 288) ? t : 575 - t;  const bool cfT = (t >= 288);
  const int idxU = (u < 288) ? u : 575 - u;  const bool cfU = (u >= 288);
  __shared__ float Xs[4][2][64];
  const int o = lane & 31, half = lane >> 5;
  #pragma unroll
  for(int m = 0; m < 2; ++m){
    int idx = m ? idxU : idxT;
    int rrow = half ? 288 + idx : idx;
    float s = 0.f;
    #pragma unroll
    for(int ks = 0; ks < 8; ++ks)
      s += xp[((size_t)(ks * NB + b) * 576 + rrow) * 32 + o];
    Xs[w][m][half * 32 + o] = s;
  }
  __syncthreads();
  float Fr[2], Fi[2];
  #pragma unroll
  for(int m = 0; m < 2; ++m){
    int idx = m ? idxU : idxT;
    int p2 = idx / 12, qq = idx - p2 * 12;
    int sel = (p2 < 12) ? 0 : 1;
    int pq = (p2 % 12) * 12 + qq;
    const float2* wb = wt + ((size_t)((layer * 2 + sel) * 144 + pq)) * 1024;
    int i0 = half * 16;
    float fr = 0.f, fi = 0.f;
    #pragma unroll
    for(int ii = 0; ii < 16; ++ii){
      int i2 = i0 + ii;
      float xr = Xs[w][m][i2], xi = Xs[w][m][32 + i2];
      float2 wv = wb[i2 * 32 + o];
      fr += xr * wv.x - xi * wv.y;
      fi += xr * wv.y + xi * wv.x;
    }
    fr += __shfl_down(fr, 32);
    fi += __shfl_down(fi, 32);
    Fr[m] = fr; Fi[m] = fi;       // valid in lanes 0..31
  }
  const int c = lane & 31;
  const int srcT = cfT ? 31 - c : c;
  const int srcU = cfU ? 31 - c : c;
  float fax = __shfl(Fr[0], srcT);
  float fay = __shfl(Fi[0], srcT);
  float fbx = __shfl(Fr[1], srcU);
  float fby = __shfl(Fi[1], srcU);
  if(lane < 32){
    float gr = fax;
    float gi = cfT ? -fay : fay;
    if(!unpaired){
      gr += fbx;
      gi -= (cfU ? -fby : fby);
    }
    unsigned short hr = f2b(gr); float lr = gr - b2f(hr);
    unsigned short hi2 = f2b(gi); float li = gi - b2f(hi2);
    size_t base = (size_t)(b * CH + c) * 576;
    ghi[base + k] = hr;          ghi[base + 288 + k] = hi2;
    glo[base + k] = f2b(lr);     glo[base + 288 + k] = f2b(li);
  }
}

// ---------- inverse transform + fused 1x1 conv (+gelu | +fc1/fc2 epilogue) ----------
// block = 32 points x 32 channels; wave w: points (w&1)*16.., channels (w>>1)*16..
template<int LAST>
__global__ __launch_bounds__(256, LAST ? 2 : 4) void k_inv(const ushort_t* __restrict__ VTF,
    const ushort_t* __restrict__ ghi, const ushort_t* __restrict__ glo,
    const float* __restrict__ hfull, const float* __restrict__ cw,
    const float* __restrict__ cbias, float* __restrict__ hout,
    ushort_t* __restrict__ houtb, int layer,
    const float* __restrict__ w1, const float* __restrict__ b1,
    const float* __restrict__ w2, const float* __restrict__ b2,
    float* __restrict__ out)
{
  __shared__ float Wl[1024];      // transposed conv W: Wl[i*32+o]
  __shared__ float Bl[32];
  __shared__ float hTc[32][33];   // conv input tile [ch][pt]
  const int tid = threadIdx.x;
  const int b = blockIdx.y;
  const int n0 = blockIdx.x * 32;
  for(int idx2 = tid; idx2 < 1024; idx2 += 256)
    Wl[(idx2 & 31) * 32 + (idx2 >> 5)] = cw[layer * 1024 + idx2];
  if(tid < 32) Bl[tid] = cbias[layer * 32 + tid];
  {
    int ch = tid >> 3, grp = tid & 7;
    float4 v = *(const float4*)(hfull + (size_t)(b * CH + ch) * NN + n0 + grp * 4);
    hTc[ch][grp * 4 + 0] = v.x; hTc[ch][grp * 4 + 1] = v.y;
    hTc[ch][grp * 4 + 2] = v.z; hTc[ch][grp * 4 + 3] = v.w;
  }
  __syncthreads();
  const int lane = tid & 63;
  const int w = tid >> 6;
  const int ng = w & 1, half = w >> 1;
  const int row = lane & 15, q = lane >> 4;
  const int nloc = ng * 16 + row;
  const int n = n0 + nloc;
  const int n16 = blockIdx.x * 2 + ng;
  const ushort_t* vb = VTF + ((size_t)(b * 512 + n16) * 18) * 512 + (q * 16 + row) * 8;
  const size_t ga = (size_t)(b * CH + half * 16 + row) * 576 + q * 8;
  floatx4 acc = {0.f,0.f,0.f,0.f};
  #pragma unroll
  for(int kk = 0; kk < 18; ++kk){
    short8 Bv = *(const short8*)(vb + (size_t)kk * 512);
    short8 Ah = *(const short8*)(ghi + ga + kk * 32);
    short8 Al = *(const short8*)(glo + ga + kk * 32);
    acc = __builtin_amdgcn_mfma_f32_16x16x32_bf16(Ah, Bv, acc, 0, 0, 0);
    acc = __builtin_amdgcn_mfma_f32_16x16x32_bf16(Al, Bv, acc, 0, 0, 0);
  }
  // conv path from LDS (fp32)
  float acc2[4];
  const int c0 = half * 16 + q * 4;
  #pragma unroll
  for(int r = 0; r < 4; ++r) acc2[r] = Bl[c0 + r];
  #pragma unroll
  for(int i = 0; i < CH; ++i){
    float hv = hTc[i][nloc];
    float4 wv = *(const float4*)&Wl[i * 32 + c0];
    acc2[0] = fmaf(hv, wv.x, acc2[0]);
    acc2[1] = fmaf(hv, wv.y, acc2[1]);
    acc2[2] = fmaf(hv, wv.z, acc2[2]);
    acc2[3] = fmaf(hv, wv.w, acc2[3]);
  }
  const float sc = 2.0f / 8192.0f;
  if constexpr(!LAST){
    #pragma unroll
    for(int r = 0; r < 4; ++r){
      int c = c0 + r;
      float v = gelu_f(acc[r] * sc + acc2[r]);
      size_t idx = (size_t)(b * CH + c) * NN + n;
      hout[idx] = v; houtb[idx] = f2b(v);
    }
  } else {
    __shared__ float hT2[32][33];
    __shared__ float Wfc1[4096];
    __shared__ float b1s[128], w2s[128];
    __shared__ float red2[256];
    #pragma unroll
    for(int r = 0; r < 4; ++r)
      hT2[nloc][c0 + r] = acc[r] * sc + acc2[r];
    for(int idx2 = tid; idx2 < 4096; idx2 += 256) Wfc1[idx2] = w1[idx2];
    if(tid < 128){ b1s[tid] = b1[tid]; w2s[tid] = w2[tid]; }
    __syncthreads();
    const int nl2 = tid & 31;
    const int js = tid >> 5;            // 8 groups of 16 j
    float acc3 = 0.f;
    for(int jj = js * 16; jj < js * 16 + 16; ++jj){
      float s = b1s[jj];
      #pragma unroll
      for(int i = 0; i < CH; ++i) s = fmaf(hT2[nl2][i], Wfc1[i * 128 + jj], s);
      acc3 = fmaf(gelu_f(s), w2s[jj], acc3);
    }
    red2[tid] = acc3;
    __syncthreads();
    if(js == 0){
      float v = b2[0];
      #pragma unroll
      for(int g2 = 0; g2 < 8; ++g2) v += red2[nl2 + g2 * 32];
      out[(size_t)b * NN + n0 + nl2] = v;
    }
  }
}

// ---------- launch ----------
extern "C" void kernel_launch(void* const* d_in, const int* in_sizes, int n_in,
                              void* d_out, int out_size, void* d_ws, size_t ws_size,
                              hipStream_t stream)
{
  const float* x      = (const float*)d_in[0];
  const float* fc0_w  = (const float*)d_in[1];
  const float* fc0_b  = (const float*)d_in[2];
  const float* spec_w = (const float*)d_in[3];
  const float* conv_w = (const float*)d_in[4];
  const float* conv_b = (const float*)d_in[5];
  const float* fc1_w  = (const float*)d_in[6];
  const float* fc1_b  = (const float*)d_in[7];
  const float* fc2_w  = (const float*)d_in[8];
  const float* fc2_b  = (const float*)d_in[9];
  float* out = (float*)d_out;

  char* w = (char*)d_ws;
  const size_t OFF_PMM  = 0;
  const size_t OFF_WT   = 4096;
  const size_t OFF_AF   = OFF_WT  + 9437184;
  const size_t OFF_VTF  = OFF_AF  + 37748736;
  const size_t OFF_H0   = OFF_VTF + 37748736;
  const size_t OFF_H1   = OFF_H0  + 4194304;
  const size_t OFF_H0B  = OFF_H1  + 4194304;
  const size_t OFF_H1B  = OFF_H0B + 2097152;
  const size_t OFF_XP   = OFF_H1B + 2097152;
  const size_t OFF_GHI  = OFF_XP  + 2359296;
  const size_t OFF_GLO  = OFF_GHI + 147456;

  float4* pmm    = (float4*)(w + OFF_PMM);
  float2* wt     = (float2*)(w + OFF_WT);
  ushort_t* AF   = (ushort_t*)(w + OFF_AF);
  ushort_t* VTF  = (ushort_t*)(w + OFF_VTF);
  float* hbuf[2]     = { (float*)(w + OFF_H0), (float*)(w + OFF_H1) };
  ushort_t* hbufb[2] = { (ushort_t*)(w + OFF_H0B), (ushort_t*)(w + OFF_H1B) };
  float* xp      = (float*)(w + OFF_XP);
  ushort_t* ghi  = (ushort_t*)(w + OFF_GHI);
  ushort_t* glo  = (ushort_t*)(w + OFF_GLO);

  hipLaunchKernelGGL(k_pre, dim3(4736), dim3(256), 0, stream, spec_w, wt, x, pmm);
  hipLaunchKernelGGL(k_vbuild, dim3(1024), dim3(256), 0, stream, x, pmm,
                     fc0_w, fc0_b, AF, VTF, hbuf[0], hbufb[0]);

  for(int l = 0; l < 4; ++l){
    int in = l & 1, outb = 1 - in;
    hipLaunchKernelGGL(k_fwd, dim3(18, 8, NB), dim3(256), 0, stream, AF, hbufb[in], xp);
    hipLaunchKernelGGL(k_mixg, dim3(72, NB), dim3(256), 0, stream, xp, wt, ghi, glo, l);
    if(l < 3)
      hipLaunchKernelGGL(k_inv<0>, dim3(256, NB), dim3(256), 0, stream, VTF, ghi, glo,
                         hbuf[in], conv_w, conv_b, hbuf[outb], hbufb[outb], l,
                         fc1_w, fc1_b, fc2_w, fc2_b, out);
    else
      hipLaunchKernelGGL(k_inv<1>, dim3(256, NB), dim3(256), 0, stream, VTF, ghi, glo,
                         hbuf[in], conv_w, conv_b, hbuf[outb], hbufb[outb], l,
                         fc1_w, fc1_b, fc2_w, fc2_b, out);
  }
  (void)in_sizes; (void)n_in; (void)out_size; (void)ws_size;
}

// Round 5
// 334.926 us; speedup vs baseline: 1.0704x; 1.0704x over previous
//
#include <hip/hip_runtime.h>
#include <cmath>

#define NB 4
#define NN 8192
#define CH 32

typedef short short8 __attribute__((ext_vector_type(8)));
typedef float floatx4 __attribute__((ext_vector_type(4)));
typedef unsigned short ushort_t;

// ---------- helpers ----------
__device__ __forceinline__ unsigned short f2b(float f){
  unsigned u = __float_as_uint(f);
  u = u + 0x7FFFu + ((u >> 16) & 1u);   // RNE
  return (unsigned short)(u >> 16);
}
__device__ __forceinline__ float b2f(unsigned short h){
  return __uint_as_float(((unsigned)h) << 16);
}
__device__ __forceinline__ float gelu_f(float v){
  return 0.5f * v * (1.0f + erff(v * 0.70710678118654752440f));
}
// rep-index closed forms (t in [0,552), t = j*24+i)
__device__ __forceinline__ int repk(int t){   // -1 if t is not a representative
  int j = t / 24, i = t - j * 24;
  if(j == 0)  return (i <= 12) ? i : -1;
  if(j <= 11) return 13 + (j - 1) * 24 + i;
  return (i == 12) ? 277 + (j - 12) : -1;
}
__device__ __forceinline__ int partner(int t){
  int j = t / 24, i = t - j * 24;
  return ((23 - j) % 23) * 24 + ((24 - i) % 24);
}
__device__ __forceinline__ int repT(int k){   // inverse of repk over reps
  if(k < 13) return k;
  if(k < 277){ int m = k - 13; return (m / 24 + 1) * 24 + (m % 24); }
  return (k - 277 + 12) * 24 + 12;
}

// ---------- fused: spec_w reorder (blocks >=128) + minmax partials (blocks <128) ----------
__global__ __launch_bounds__(256) void k_pre(const float* __restrict__ spec,
    float2* __restrict__ wt, const float* __restrict__ x, float4* __restrict__ pmm)
{
  const int tid = threadIdx.x;
  if(blockIdx.x < 128){
    int g = blockIdx.x * 256 + tid;           // 32768 threads
    float a = x[(size_t)g * 2], b = x[(size_t)g * 2 + 1];
    float mn0 = a, mx0 = a, mn1 = b, mx1 = b;
    for(int off = 32; off > 0; off >>= 1){
      mn0 = fminf(mn0, __shfl_down(mn0, off));
      mx0 = fmaxf(mx0, __shfl_down(mx0, off));
      mn1 = fminf(mn1, __shfl_down(mn1, off));
      mx1 = fmaxf(mx1, __shfl_down(mx1, off));
    }
    __shared__ float4 wp[4];
    if((tid & 63) == 0) wp[tid >> 6] = make_float4(mn0, mn1, mx0, mx1);
    __syncthreads();
    if(tid == 0){
      float4 r = wp[0];
      for(int i2 = 1; i2 < 4; ++i2){
        float4 v = wp[i2];
        r.x = fminf(r.x, v.x); r.y = fminf(r.y, v.y);
        r.z = fmaxf(r.z, v.z); r.w = fmaxf(r.w, v.w);
      }
      pmm[blockIdx.x] = r;
    }
  } else {
    int g = (blockIdx.x - 128) * 256 + tid;   // 1,179,648
    int o  = g & 31;
    int i  = (g >> 5) & 31;
    int rest = g >> 10;
    int pq = rest % 144;
    int ls = rest / 144;                      // l*2+sel
    wt[g] = ((const float2*)spec)[(((size_t)(ls * 32 + i) * 32 + o) * 144 + pq)];
  }
}

// ---------- build V in MFMA-fragment layouts + fc0 ----------
// AF : forward A-operand.  [b][st=36][ng=256][q=4][srow=16][e=8] shorts
// VTF: inverse B-operand.  [b][n16=512][kk=18][q=4][n15=16][e=8] shorts
__global__ __launch_bounds__(256) void k_vbuild(const float* __restrict__ x,
    const float4* __restrict__ pmm, const float* __restrict__ fw,
    const float* __restrict__ fb, ushort_t* __restrict__ AF, ushort_t* __restrict__ VTF,
    float* __restrict__ h, ushort_t* __restrict__ hb)
{
  __shared__ ushort_t lds1[32 * 584];
  __shared__ float4 mmv;
  const int tid = threadIdx.x;
  if(tid < 64){
    float4 a = pmm[tid], c = pmm[tid + 64];
    float mn0 = fminf(a.x, c.x), mn1 = fminf(a.y, c.y);
    float mx0 = fmaxf(a.z, c.z), mx1 = fmaxf(a.w, c.w);
    for(int off = 32; off > 0; off >>= 1){
      mn0 = fminf(mn0, __shfl_down(mn0, off));
      mn1 = fminf(mn1, __shfl_down(mn1, off));
      mx0 = fmaxf(mx0, __shfl_down(mx0, off));
      mx1 = fmaxf(mx1, __shfl_down(mx1, off));
    }
    if(tid == 0) mmv = make_float4(mn0, mn1, mx0, mx1);
  }
  __syncthreads();
  const int nl = tid & 31, part = tid >> 5;
  const int b = blockIdx.x >> 8;
  const int nblk = blockIdx.x & 255;
  const int n = nblk * 32 + nl;
  float mn0 = mmv.x, mn1 = mmv.y, mx0 = mmv.z, mx1 = mmv.w;
  float x0 = x[(size_t)(b * NN + n) * 2]     - mn0;
  float x1 = x[(size_t)(b * NN + n) * 2 + 1] - mn1;
  float sp = x0 * (6.28f / (mx0 - mn0));
  float sq = x1 * (6.28f / (mx1 - mn1));
  float cx, sx, cy, sy;
  sincosf(sp, &sx, &cx);
  sincosf(sq, &sy, &cy);
  int j0 = part * 3;
  int j1 = (j0 + 3 < 23) ? j0 + 3 : 23;
  float ky0 = (j0 < 12) ? (float)j0 : (float)(j0 - 23);
  float cb, sb;
  sincosf(ky0 * sq, &sb, &cb);
  for(int j = j0; j < j1; ++j){
    float ca = 1.0f, sa = 0.0f;   // kx = 0
    #pragma unroll
    for(int i = 0; i < 24; ++i){
      float vr = ca * cb - sa * sb;        //  cos(kx*sp + ky*sq)
      float vi = -(sa * cb + ca * sb);     // -sin(kx*sp + ky*sq)
      int t = j * 24 + i;
      int k = repk(t);
      if(k >= 0){
        lds1[nl * 584 + k]       = f2b(vr);
        lds1[nl * 584 + 288 + k] = f2b(vi);
      }
      float cn = ca * cx - sa * sx;
      float sn = sa * cx + ca * sx;
      if(i == 11) sn = -sn;                // kx 11 -> -12 (conjugate)
      ca = cn; sa = sn;
    }
    float cbn = cb * cy - sb * sy;
    float sbn = sb * cy + cb * sy;
    cb = cbn; sb = sbn;
  }
  __syncthreads();
  // phase-1 emission: VTF (coalesced 16B/lane)
  #pragma unroll
  for(int r = 0; r < 9; ++r){
    int c = tid + 256 * r;                  // [0,2304)
    int t16 = c / 1152;
    int c2 = c - t16 * 1152;
    int kk = c2 >> 6;
    int rem = c2 & 63;
    int q = rem >> 4, n15 = rem & 15;
    short8 v = *(const short8*)(lds1 + (t16 * 16 + n15) * 584 + kk * 32 + q * 8);
    *(short8*)(VTF + ((size_t)((b * 512 + nblk * 2 + t16) * 18 + kk)) * 512
               + (q * 16 + n15) * 8) = v;
  }
  // phase-2 emission: AF via conjugate symmetry from LDS
  #pragma unroll
  for(int r = 0; r < 9; ++r){
    int c = tid + 256 * r;                  // [0,2304)
    int st = c >> 6;
    int rem = c & 63;
    int q = rem >> 4, srow = rem & 15;
    int sg = st * 16 + srow;                // [0,576)
    int s = (sg < 288) ? sg : sg - 288;
    int sinh_ = (sg >= 288);
    int p2 = s / 12, qq = s - p2 * 12;
    int t = p2 * 23 + qq;
    int k = repk(t);
    unsigned short flip = 0;
    if(k < 0){ k = repk(partner(t)); if(sinh_) flip = 0x8000; }
    int col = sinh_ ? 288 + k : k;
    ushort_t tmp[8];
    #pragma unroll
    for(int e = 0; e < 8; ++e)
      tmp[e] = lds1[(q * 8 + e) * 584 + col] ^ flip;
    *(short8*)(AF + ((size_t)((b * 36 + st) * 256 + nblk)) * 512
               + (q * 16 + srow) * 8) = *(short8*)tmp;
  }
  // fused fc0
  #pragma unroll
  for(int rr = 0; rr < 4; ++rr){
    int c2 = (tid >> 5) + rr * 8;
    float v = fb[c2] + x0 * fw[c2] + x1 * fw[32 + c2];
    size_t idx = (size_t)(b * CH + c2) * NN + n;
    h[idx] = v; hb[idx] = f2b(v);
  }
}

// ---------- forward transform (K-split 8, 2 s-tiles/block): xp[ks][b][576][32] ----------
__global__ __launch_bounds__(256) void k_fwd(const ushort_t* __restrict__ AF,
    const ushort_t* __restrict__ hb, float* __restrict__ xp)
{
  const int stp = blockIdx.x;      // 18 pairs
  const int ks = blockIdx.y;       // 8
  const int b  = blockIdx.z;
  const int w = threadIdx.x >> 6;
  const int lane = threadIdx.x & 63;
  const int row = lane & 15;
  const int q = lane >> 4;
  const int st0 = stp * 2;
  const size_t abase0 = ((size_t)(b * 36 + st0) * 256) * 512 + (q * 16 + row) * 8;
  const size_t abase1 = abase0 + (size_t)256 * 512;
  const size_t hb0 = (size_t)(b * CH + row) * NN;
  const size_t hb1 = hb0 + (size_t)16 * NN;
  floatx4 aA0 = {0.f,0.f,0.f,0.f}, aA1 = {0.f,0.f,0.f,0.f};
  floatx4 aB0 = {0.f,0.f,0.f,0.f}, aB1 = {0.f,0.f,0.f,0.f};
  #pragma unroll
  for(int kk = 0; kk < 8; ++kk){
    int g = ks * 32 + w * 8 + kk;
    short8 A0 = *(const short8*)(AF + abase0 + (size_t)g * 512);
    short8 A1 = *(const short8*)(AF + abase1 + (size_t)g * 512);
    int nn2 = g * 32 + q * 8;
    short8 B0 = *(const short8*)(hb + hb0 + nn2);
    short8 B1 = *(const short8*)(hb + hb1 + nn2);
    aA0 = __builtin_amdgcn_mfma_f32_16x16x32_bf16(A0, B0, aA0, 0, 0, 0);
    aA1 = __builtin_amdgcn_mfma_f32_16x16x32_bf16(A0, B1, aA1, 0, 0, 0);
    aB0 = __builtin_amdgcn_mfma_f32_16x16x32_bf16(A1, B0, aB0, 0, 0, 0);
    aB1 = __builtin_amdgcn_mfma_f32_16x16x32_bf16(A1, B1, aB1, 0, 0, 0);
  }
  __shared__ float red[4 * 512];
  const int e = threadIdx.x;
  #pragma unroll
  for(int r = 0; r < 4; ++r){
    int rrow = q * 4 + r;
    red[w * 512 + rrow * 32 + row]      = aA0[r];
    red[w * 512 + rrow * 32 + 16 + row] = aA1[r];
  }
  __syncthreads();
  {
    float v0 = red[e] + red[512 + e] + red[1024 + e] + red[1536 + e];
    float v1 = red[e + 256] + red[512 + e + 256] + red[1024 + e + 256] + red[1536 + e + 256];
    size_t base = ((size_t)(ks * NB + b) * 576 + st0 * 16) * 32;
    xp[base + e] = v0;
    xp[base + e + 256] = v1;
  }
  __syncthreads();
  #pragma unroll
  for(int r = 0; r < 4; ++r){
    int rrow = q * 4 + r;
    red[w * 512 + rrow * 32 + row]      = aB0[r];
    red[w * 512 + rrow * 32 + 16 + row] = aB1[r];
  }
  __syncthreads();
  {
    float v0 = red[e] + red[512 + e] + red[1024 + e] + red[1536 + e];
    float v1 = red[e + 256] + red[512 + e + 256] + red[1024 + e + 256] + red[1536 + e + 256];
    size_t base = ((size_t)(ks * NB + b) * 576 + (st0 + 1) * 16) * 32;
    xp[base + e] = v0;
    xp[base + e + 256] = v1;
  }
}

// ---------- fused mix + fold -> ghi/glo (wave per rep, 4 reps/block) ----------
__global__ __launch_bounds__(256) void k_mixg(const float* __restrict__ xp,
    const float2* __restrict__ wt, ushort_t* __restrict__ ghi, ushort_t* __restrict__ glo,
    int layer)
{
  const int w = threadIdx.x >> 6;
  const int lane = threadIdx.x & 63;
  const int k = blockIdx.x * 4 + w;    // 288 reps
  const int b = blockIdx.y;
  const int t = repT(k);
  const int j = t / 24, i = t - j * 24;
  const int u = partner(t);
  const bool unpaired = (i == 12) || (u == t);
  const int idxT = (t < 288) ? t : 575 - t;  const bool cfT = (t >= 288);
  const int idxU = (u < 288) ? u : 575 - u;  const bool cfU = (u >= 288);
  __shared__ float Xs[4][2][64];
  const int o = lane & 31, half = lane >> 5;
  #pragma unroll
  for(int m = 0; m < 2; ++m){
    int idx = m ? idxU : idxT;
    int rrow = half ? 288 + idx : idx;
    float s = 0.f;
    #pragma unroll
    for(int ks = 0; ks < 8; ++ks)
      s += xp[((size_t)(ks * NB + b) * 576 + rrow) * 32 + o];
    Xs[w][m][half * 32 + o] = s;
  }
  __syncthreads();
  float Fr[2], Fi[2];
  #pragma unroll
  for(int m = 0; m < 2; ++m){
    int idx = m ? idxU : idxT;
    int p2 = idx / 12, qq = idx - p2 * 12;
    int sel = (p2 < 12) ? 0 : 1;
    int pq = (p2 % 12) * 12 + qq;
    const float2* wb = wt + ((size_t)((layer * 2 + sel) * 144 + pq)) * 1024;
    int i0 = half * 16;
    float fr = 0.f, fi = 0.f;
    #pragma unroll
    for(int ii = 0; ii < 16; ++ii){
      int i2 = i0 + ii;
      float xr = Xs[w][m][i2], xi = Xs[w][m][32 + i2];
      float2 wv = wb[i2 * 32 + o];
      fr += xr * wv.x - xi * wv.y;
      fi += xr * wv.y + xi * wv.x;
    }
    fr += __shfl_down(fr, 32);
    fi += __shfl_down(fi, 32);
    Fr[m] = fr; Fi[m] = fi;       // valid in lanes 0..31
  }
  const int c = lane & 31;
  const int srcT = cfT ? 31 - c : c;
  const int srcU = cfU ? 31 - c : c;
  float fax = __shfl(Fr[0], srcT);
  float fay = __shfl(Fi[0], srcT);
  float fbx = __shfl(Fr[1], srcU);
  float fby = __shfl(Fi[1], srcU);
  if(lane < 32){
    float gr = fax;
    float gi = cfT ? -fay : fay;
    if(!unpaired){
      gr += fbx;
      gi -= (cfU ? -fby : fby);
    }
    unsigned short hr = f2b(gr); float lr = gr - b2f(hr);
    unsigned short hi2 = f2b(gi); float li = gi - b2f(hi2);
    size_t base = (size_t)(b * CH + c) * 576;
    ghi[base + k] = hr;          ghi[base + 288 + k] = hi2;
    glo[base + k] = f2b(lr);     glo[base + 288 + k] = f2b(li);
  }
}

// ---------- inverse transform + fused 1x1 conv (+gelu | +fc1/fc2 epilogue) ----------
// R2 structure: block = 64 points (4 n16-tiles, one per wave), all 32 channels per wave.
// Conv input staged in LDS (removes the serial per-i global-load chain).
template<int LAST>
__global__ __launch_bounds__(256, 2) void k_inv(const ushort_t* __restrict__ VTF,
    const ushort_t* __restrict__ ghi, const ushort_t* __restrict__ glo,
    const float* __restrict__ hfull, const float* __restrict__ cw,
    const float* __restrict__ cbias, float* __restrict__ hout,
    ushort_t* __restrict__ houtb, int layer,
    const float* __restrict__ w1, const float* __restrict__ b1,
    const float* __restrict__ w2, const float* __restrict__ b2,
    float* __restrict__ out)
{
  __shared__ float Wl[1024];      // transposed conv W: Wl[i*32+o]
  __shared__ float Bl[32];
  __shared__ float hTc[32][65];   // conv input tile [ch][pt 0..63]
  const int tid = threadIdx.x;
  const int b = blockIdx.y;
  const int n0 = blockIdx.x * 64;
  for(int idx2 = tid; idx2 < 1024; idx2 += 256)
    Wl[(idx2 & 31) * 32 + (idx2 >> 5)] = cw[layer * 1024 + idx2];
  if(tid < 32) Bl[tid] = cbias[layer * 32 + tid];
  {
    int ch = tid >> 3, grp = tid & 7;
    const float* src = hfull + (size_t)(b * CH + ch) * NN + n0 + grp * 8;
    float4 v0 = *(const float4*)src;
    float4 v1 = *(const float4*)(src + 4);
    int p = grp * 8;
    hTc[ch][p + 0] = v0.x; hTc[ch][p + 1] = v0.y;
    hTc[ch][p + 2] = v0.z; hTc[ch][p + 3] = v0.w;
    hTc[ch][p + 4] = v1.x; hTc[ch][p + 5] = v1.y;
    hTc[ch][p + 6] = v1.z; hTc[ch][p + 7] = v1.w;
  }
  __syncthreads();
  const int lane = tid & 63;
  const int w = tid >> 6;
  const int row = lane & 15;
  const int q = lane >> 4;
  const int nloc = w * 16 + row;
  const int n = n0 + nloc;
  const int n16 = blockIdx.x * 4 + w;
  const ushort_t* vb = VTF + ((size_t)(b * 512 + n16) * 18) * 512 + (q * 16 + row) * 8;
  const size_t g0 = (size_t)(b * CH + row) * 576 + q * 8;
  const size_t g1 = g0 + (size_t)16 * 576;
  floatx4 acc0 = {0.f,0.f,0.f,0.f}, acc1 = {0.f,0.f,0.f,0.f};
  for(int kk = 0; kk < 18; ++kk){
    short8 Bv  = *(const short8*)(vb + (size_t)kk * 512);
    short8 Ah0 = *(const short8*)(ghi + g0 + kk * 32);
    short8 Al0 = *(const short8*)(glo + g0 + kk * 32);
    short8 Ah1 = *(const short8*)(ghi + g1 + kk * 32);
    short8 Al1 = *(const short8*)(glo + g1 + kk * 32);
    acc0 = __builtin_amdgcn_mfma_f32_16x16x32_bf16(Ah0, Bv, acc0, 0, 0, 0);
    acc0 = __builtin_amdgcn_mfma_f32_16x16x32_bf16(Al0, Bv, acc0, 0, 0, 0);
    acc1 = __builtin_amdgcn_mfma_f32_16x16x32_bf16(Ah1, Bv, acc1, 0, 0, 0);
    acc1 = __builtin_amdgcn_mfma_f32_16x16x32_bf16(Al1, Bv, acc1, 0, 0, 0);
  }
  // conv path from LDS (fp32, same summation order as before -> bitwise identical)
  float acc2[8];
  {
    const int c0 = q * 4;
    #pragma unroll
    for(int r = 0; r < 4; ++r){ acc2[r] = Bl[c0 + r]; acc2[4 + r] = Bl[16 + c0 + r]; }
    #pragma unroll
    for(int i = 0; i < CH; ++i){
      float hv = hTc[i][nloc];
      float4 wv0 = *(const float4*)&Wl[i * 32 + c0];
      float4 wv1 = *(const float4*)&Wl[i * 32 + 16 + c0];
      acc2[0] = fmaf(hv, wv0.x, acc2[0]);
      acc2[1] = fmaf(hv, wv0.y, acc2[1]);
      acc2[2] = fmaf(hv, wv0.z, acc2[2]);
      acc2[3] = fmaf(hv, wv0.w, acc2[3]);
      acc2[4] = fmaf(hv, wv1.x, acc2[4]);
      acc2[5] = fmaf(hv, wv1.y, acc2[5]);
      acc2[6] = fmaf(hv, wv1.z, acc2[6]);
      acc2[7] = fmaf(hv, wv1.w, acc2[7]);
    }
  }
  const float sc = 2.0f / 8192.0f;
  if constexpr(!LAST){
    #pragma unroll
    for(int r = 0; r < 4; ++r){
      int c = q * 4 + r;
      float v0 = gelu_f(acc0[r] * sc + acc2[r]);
      size_t idx0 = (size_t)(b * CH + c) * NN + n;
      hout[idx0] = v0; houtb[idx0] = f2b(v0);
      float v1 = gelu_f(acc1[r] * sc + acc2[4 + r]);
      size_t idx1 = (size_t)(b * CH + 16 + c) * NN + n;
      hout[idx1] = v1; houtb[idx1] = f2b(v1);
    }
  } else {
    __shared__ float hT2[64][33];
    __shared__ float Wfc1[4096];
    __shared__ float b1s[128], w2s[128];
    __shared__ float red2[256];
    #pragma unroll
    for(int r = 0; r < 4; ++r){
      int c = q * 4 + r;
      hT2[nloc][c]      = acc0[r] * sc + acc2[r];
      hT2[nloc][16 + c] = acc1[r] * sc + acc2[4 + r];
    }
    for(int idx2 = tid; idx2 < 4096; idx2 += 256) Wfc1[idx2] = w1[idx2];
    if(tid < 128){ b1s[tid] = b1[tid]; w2s[tid] = w2[tid]; }
    __syncthreads();
    const int nl2 = tid & 63;
    const int js = tid >> 6;            // 4 groups of 32 j
    float acc3 = 0.f;
    for(int jj = js * 32; jj < js * 32 + 32; ++jj){
      float s = b1s[jj];
      #pragma unroll
      for(int i = 0; i < CH; ++i) s = fmaf(hT2[nl2][i], Wfc1[i * 128 + jj], s);
      acc3 = fmaf(gelu_f(s), w2s[jj], acc3);
    }
    red2[tid] = acc3;
    __syncthreads();
    if(js == 0){
      float v = red2[nl2] + red2[nl2 + 64] + red2[nl2 + 128] + red2[nl2 + 192] + b2[0];
      out[(size_t)b * NN + n0 + nl2] = v;
    }
  }
}

// ---------- launch ----------
extern "C" void kernel_launch(void* const* d_in, const int* in_sizes, int n_in,
                              void* d_out, int out_size, void* d_ws, size_t ws_size,
                              hipStream_t stream)
{
  const float* x      = (const float*)d_in[0];
  const float* fc0_w  = (const float*)d_in[1];
  const float* fc0_b  = (const float*)d_in[2];
  const float* spec_w = (const float*)d_in[3];
  const float* conv_w = (const float*)d_in[4];
  const float* conv_b = (const float*)d_in[5];
  const float* fc1_w  = (const float*)d_in[6];
  const float* fc1_b  = (const float*)d_in[7];
  const float* fc2_w  = (const float*)d_in[8];
  const float* fc2_b  = (const float*)d_in[9];
  float* out = (float*)d_out;

  char* w = (char*)d_ws;
  const size_t OFF_PMM  = 0;
  const size_t OFF_WT   = 4096;
  const size_t OFF_AF   = OFF_WT  + 9437184;
  const size_t OFF_VTF  = OFF_AF  + 37748736;
  const size_t OFF_H0   = OFF_VTF + 37748736;
  const size_t OFF_H1   = OFF_H0  + 4194304;
  const size_t OFF_H0B  = OFF_H1  + 4194304;
  const size_t OFF_H1B  = OFF_H0B + 2097152;
  const size_t OFF_XP   = OFF_H1B + 2097152;
  const size_t OFF_GHI  = OFF_XP  + 2359296;
  const size_t OFF_GLO  = OFF_GHI + 147456;

  float4* pmm    = (float4*)(w + OFF_PMM);
  float2* wt     = (float2*)(w + OFF_WT);
  ushort_t* AF   = (ushort_t*)(w + OFF_AF);
  ushort_t* VTF  = (ushort_t*)(w + OFF_VTF);
  float* hbuf[2]     = { (float*)(w + OFF_H0), (float*)(w + OFF_H1) };
  ushort_t* hbufb[2] = { (ushort_t*)(w + OFF_H0B), (ushort_t*)(w + OFF_H1B) };
  float* xp      = (float*)(w + OFF_XP);
  ushort_t* ghi  = (ushort_t*)(w + OFF_GHI);
  ushort_t* glo  = (ushort_t*)(w + OFF_GLO);

  hipLaunchKernelGGL(k_pre, dim3(4736), dim3(256), 0, stream, spec_w, wt, x, pmm);
  hipLaunchKernelGGL(k_vbuild, dim3(1024), dim3(256), 0, stream, x, pmm,
                     fc0_w, fc0_b, AF, VTF, hbuf[0], hbufb[0]);

  for(int l = 0; l < 4; ++l){
    int in = l & 1, outb = 1 - in;
    hipLaunchKernelGGL(k_fwd, dim3(18, 8, NB), dim3(256), 0, stream, AF, hbufb[in], xp);
    hipLaunchKernelGGL(k_mixg, dim3(72, NB), dim3(256), 0, stream, xp, wt, ghi, glo, l);
    if(l < 3)
      hipLaunchKernelGGL(k_inv<0>, dim3(128, NB), dim3(256), 0, stream, VTF, ghi, glo,
                         hbuf[in], conv_w, conv_b, hbuf[outb], hbufb[outb], l,
                         fc1_w, fc1_b, fc2_w, fc2_b, out);
    else
      hipLaunchKernelGGL(k_inv<1>, dim3(128, NB), dim3(256), 0, stream, VTF, ghi, glo,
                         hbuf[in], conv_w, conv_b, hbuf[outb], hbufb[outb], l,
                         fc1_w, fc1_b, fc2_w, fc2_b, out);
  }
  (void)in_sizes; (void)n_in; (void)out_size; (void)ws_size;
}

// Round 6
// 255.876 us; speedup vs baseline: 1.4010x; 1.3089x over previous
//
#include <hip/hip_runtime.h>
#include <cmath>

#define NB 4
#define NN 8192
#define CH 32

typedef short short8 __attribute__((ext_vector_type(8)));
typedef float floatx4 __attribute__((ext_vector_type(4)));
typedef unsigned short ushort_t;

// ---------- helpers ----------
__device__ __forceinline__ unsigned short f2b(float f){
  unsigned u = __float_as_uint(f);
  u = u + 0x7FFFu + ((u >> 16) & 1u);   // RNE
  return (unsigned short)(u >> 16);
}
__device__ __forceinline__ float b2f(unsigned short h){
  return __uint_as_float(((unsigned)h) << 16);
}
__device__ __forceinline__ float gelu_f(float v){
  return 0.5f * v * (1.0f + erff(v * 0.70710678118654752440f));
}
// rep-index closed forms (t in [0,552), t = j*24+i)
__device__ __forceinline__ int repk(int t){   // -1 if t is not a representative
  int j = t / 24, i = t - j * 24;
  if(j == 0)  return (i <= 12) ? i : -1;
  if(j <= 11) return 13 + (j - 1) * 24 + i;
  return (i == 12) ? 277 + (j - 12) : -1;
}
__device__ __forceinline__ int partner(int t){
  int j = t / 24, i = t - j * 24;
  return ((23 - j) % 23) * 24 + ((24 - i) % 24);
}
__device__ __forceinline__ int repT(int k){   // inverse of repk over reps
  if(k < 13) return k;
  if(k < 277){ int m = k - 13; return (m / 24 + 1) * 24 + (m % 24); }
  return (k - 277 + 12) * 24 + 12;
}

// ---------- fused: spec_w reorder (blocks >=128) + minmax partials (blocks <128) ----------
__global__ __launch_bounds__(256) void k_pre(const float* __restrict__ spec,
    float2* __restrict__ wt, const float* __restrict__ x, float4* __restrict__ pmm)
{
  const int tid = threadIdx.x;
  if(blockIdx.x < 128){
    int g = blockIdx.x * 256 + tid;           // 32768 threads
    float a = x[(size_t)g * 2], b = x[(size_t)g * 2 + 1];
    float mn0 = a, mx0 = a, mn1 = b, mx1 = b;
    for(int off = 32; off > 0; off >>= 1){
      mn0 = fminf(mn0, __shfl_down(mn0, off));
      mx0 = fmaxf(mx0, __shfl_down(mx0, off));
      mn1 = fminf(mn1, __shfl_down(mn1, off));
      mx1 = fmaxf(mx1, __shfl_down(mx1, off));
    }
    __shared__ float4 wp[4];
    if((tid & 63) == 0) wp[tid >> 6] = make_float4(mn0, mn1, mx0, mx1);
    __syncthreads();
    if(tid == 0){
      float4 r = wp[0];
      for(int i2 = 1; i2 < 4; ++i2){
        float4 v = wp[i2];
        r.x = fminf(r.x, v.x); r.y = fminf(r.y, v.y);
        r.z = fmaxf(r.z, v.z); r.w = fmaxf(r.w, v.w);
      }
      pmm[blockIdx.x] = r;
    }
  } else {
    int g = (blockIdx.x - 128) * 256 + tid;   // 1,179,648
    int o  = g & 31;
    int i  = (g >> 5) & 31;
    int rest = g >> 10;
    int pq = rest % 144;
    int ls = rest / 144;                      // l*2+sel
    wt[g] = ((const float2*)spec)[(((size_t)(ls * 32 + i) * 32 + o) * 144 + pq)];
  }
}

// ---------- build V in MFMA-fragment layouts + fc0 ----------
// AF : forward A-operand.  [b][st=36][ng=256][q=4][srow=16][e=8] shorts
// VTF: inverse B-operand.  [b][n16=512][kk=18][q=4][n15=16][e=8] shorts
__global__ __launch_bounds__(256) void k_vbuild(const float* __restrict__ x,
    const float4* __restrict__ pmm, const float* __restrict__ fw,
    const float* __restrict__ fb, ushort_t* __restrict__ AF, ushort_t* __restrict__ VTF,
    float* __restrict__ h, ushort_t* __restrict__ hb)
{
  __shared__ ushort_t lds1[32 * 584];
  __shared__ float4 mmv;
  const int tid = threadIdx.x;
  if(tid < 64){
    float4 a = pmm[tid], c = pmm[tid + 64];
    float mn0 = fminf(a.x, c.x), mn1 = fminf(a.y, c.y);
    float mx0 = fmaxf(a.z, c.z), mx1 = fmaxf(a.w, c.w);
    for(int off = 32; off > 0; off >>= 1){
      mn0 = fminf(mn0, __shfl_down(mn0, off));
      mn1 = fminf(mn1, __shfl_down(mn1, off));
      mx0 = fmaxf(mx0, __shfl_down(mx0, off));
      mx1 = fmaxf(mx1, __shfl_down(mx1, off));
    }
    if(tid == 0) mmv = make_float4(mn0, mn1, mx0, mx1);
  }
  __syncthreads();
  const int nl = tid & 31, part = tid >> 5;
  const int b = blockIdx.x >> 8;
  const int nblk = blockIdx.x & 255;
  const int n = nblk * 32 + nl;
  float mn0 = mmv.x, mn1 = mmv.y, mx0 = mmv.z, mx1 = mmv.w;
  float x0 = x[(size_t)(b * NN + n) * 2]     - mn0;
  float x1 = x[(size_t)(b * NN + n) * 2 + 1] - mn1;
  float sp = x0 * (6.28f / (mx0 - mn0));
  float sq = x1 * (6.28f / (mx1 - mn1));
  float cx, sx, cy, sy;
  sincosf(sp, &sx, &cx);
  sincosf(sq, &sy, &cy);
  int j0 = part * 3;
  int j1 = (j0 + 3 < 23) ? j0 + 3 : 23;
  float ky0 = (j0 < 12) ? (float)j0 : (float)(j0 - 23);
  float cb, sb;
  sincosf(ky0 * sq, &sb, &cb);
  for(int j = j0; j < j1; ++j){
    float ca = 1.0f, sa = 0.0f;   // kx = 0
    #pragma unroll
    for(int i = 0; i < 24; ++i){
      float vr = ca * cb - sa * sb;        //  cos(kx*sp + ky*sq)
      float vi = -(sa * cb + ca * sb);     // -sin(kx*sp + ky*sq)
      int t = j * 24 + i;
      int k = repk(t);
      if(k >= 0){
        lds1[nl * 584 + k]       = f2b(vr);
        lds1[nl * 584 + 288 + k] = f2b(vi);
      }
      float cn = ca * cx - sa * sx;
      float sn = sa * cx + ca * sx;
      if(i == 11) sn = -sn;                // kx 11 -> -12 (conjugate)
      ca = cn; sa = sn;
    }
    float cbn = cb * cy - sb * sy;
    float sbn = sb * cy + cb * sy;
    cb = cbn; sb = sbn;
  }
  __syncthreads();
  // phase-1 emission: VTF (coalesced 16B/lane)
  #pragma unroll
  for(int r = 0; r < 9; ++r){
    int c = tid + 256 * r;                  // [0,2304)
    int t16 = c / 1152;
    int c2 = c - t16 * 1152;
    int kk = c2 >> 6;
    int rem = c2 & 63;
    int q = rem >> 4, n15 = rem & 15;
    short8 v = *(const short8*)(lds1 + (t16 * 16 + n15) * 584 + kk * 32 + q * 8);
    *(short8*)(VTF + ((size_t)((b * 512 + nblk * 2 + t16) * 18 + kk)) * 512
               + (q * 16 + n15) * 8) = v;
  }
  // phase-2 emission: AF via conjugate symmetry from LDS
  #pragma unroll
  for(int r = 0; r < 9; ++r){
    int c = tid + 256 * r;                  // [0,2304)
    int st = c >> 6;
    int rem = c & 63;
    int q = rem >> 4, srow = rem & 15;
    int sg = st * 16 + srow;                // [0,576)
    int s = (sg < 288) ? sg : sg - 288;
    int sinh_ = (sg >= 288);
    int p2 = s / 12, qq = s - p2 * 12;
    int t = p2 * 23 + qq;
    int k = repk(t);
    unsigned short flip = 0;
    if(k < 0){ k = repk(partner(t)); if(sinh_) flip = 0x8000; }
    int col = sinh_ ? 288 + k : k;
    ushort_t tmp[8];
    #pragma unroll
    for(int e = 0; e < 8; ++e)
      tmp[e] = lds1[(q * 8 + e) * 584 + col] ^ flip;
    *(short8*)(AF + ((size_t)((b * 36 + st) * 256 + nblk)) * 512
               + (q * 16 + srow) * 8) = *(short8*)tmp;
  }
  // fused fc0
  #pragma unroll
  for(int rr = 0; rr < 4; ++rr){
    int c2 = (tid >> 5) + rr * 8;
    float v = fb[c2] + x0 * fw[c2] + x1 * fw[32 + c2];
    size_t idx = (size_t)(b * CH + c2) * NN + n;
    h[idx] = v; hb[idx] = f2b(v);
  }
}

// ---------- forward transform (K-split 8, 2 s-tiles/block): xp[ks][b][576][32] ----------
__global__ __launch_bounds__(256) void k_fwd(const ushort_t* __restrict__ AF,
    const ushort_t* __restrict__ hb, float* __restrict__ xp)
{
  const int stp = blockIdx.x;      // 18 pairs
  const int ks = blockIdx.y;       // 8
  const int b  = blockIdx.z;
  const int w = threadIdx.x >> 6;
  const int lane = threadIdx.x & 63;
  const int row = lane & 15;
  const int q = lane >> 4;
  const int st0 = stp * 2;
  const size_t abase0 = ((size_t)(b * 36 + st0) * 256) * 512 + (q * 16 + row) * 8;
  const size_t abase1 = abase0 + (size_t)256 * 512;
  const size_t hb0 = (size_t)(b * CH + row) * NN;
  const size_t hb1 = hb0 + (size_t)16 * NN;
  floatx4 aA0 = {0.f,0.f,0.f,0.f}, aA1 = {0.f,0.f,0.f,0.f};
  floatx4 aB0 = {0.f,0.f,0.f,0.f}, aB1 = {0.f,0.f,0.f,0.f};
  #pragma unroll
  for(int kk = 0; kk < 8; ++kk){
    int g = ks * 32 + w * 8 + kk;
    short8 A0 = *(const short8*)(AF + abase0 + (size_t)g * 512);
    short8 A1 = *(const short8*)(AF + abase1 + (size_t)g * 512);
    int nn2 = g * 32 + q * 8;
    short8 B0 = *(const short8*)(hb + hb0 + nn2);
    short8 B1 = *(const short8*)(hb + hb1 + nn2);
    aA0 = __builtin_amdgcn_mfma_f32_16x16x32_bf16(A0, B0, aA0, 0, 0, 0);
    aA1 = __builtin_amdgcn_mfma_f32_16x16x32_bf16(A0, B1, aA1, 0, 0, 0);
    aB0 = __builtin_amdgcn_mfma_f32_16x16x32_bf16(A1, B0, aB0, 0, 0, 0);
    aB1 = __builtin_amdgcn_mfma_f32_16x16x32_bf16(A1, B1, aB1, 0, 0, 0);
  }
  __shared__ float red[4 * 512];
  const int e = threadIdx.x;
  #pragma unroll
  for(int r = 0; r < 4; ++r){
    int rrow = q * 4 + r;
    red[w * 512 + rrow * 32 + row]      = aA0[r];
    red[w * 512 + rrow * 32 + 16 + row] = aA1[r];
  }
  __syncthreads();
  {
    float v0 = red[e] + red[512 + e] + red[1024 + e] + red[1536 + e];
    float v1 = red[e + 256] + red[512 + e + 256] + red[1024 + e + 256] + red[1536 + e + 256];
    size_t base = ((size_t)(ks * NB + b) * 576 + st0 * 16) * 32;
    xp[base + e] = v0;
    xp[base + e + 256] = v1;
  }
  __syncthreads();
  #pragma unroll
  for(int r = 0; r < 4; ++r){
    int rrow = q * 4 + r;
    red[w * 512 + rrow * 32 + row]      = aB0[r];
    red[w * 512 + rrow * 32 + 16 + row] = aB1[r];
  }
  __syncthreads();
  {
    float v0 = red[e] + red[512 + e] + red[1024 + e] + red[1536 + e];
    float v1 = red[e + 256] + red[512 + e + 256] + red[1024 + e + 256] + red[1536 + e + 256];
    size_t base = ((size_t)(ks * NB + b) * 576 + (st0 + 1) * 16) * 32;
    xp[base + e] = v0;
    xp[base + e + 256] = v1;
  }
}

// ---------- fused mix + fold -> ghi/glo (wave per rep, 4 reps/block) ----------
__global__ __launch_bounds__(256) void k_mixg(const float* __restrict__ xp,
    const float2* __restrict__ wt, ushort_t* __restrict__ ghi, ushort_t* __restrict__ glo,
    int layer)
{
  const int w = threadIdx.x >> 6;
  const int lane = threadIdx.x & 63;
  const int k = blockIdx.x * 4 + w;    // 288 reps
  const int b = blockIdx.y;
  const int t = repT(k);
  const int j = t / 24, i = t - j * 24;
  const int u = partner(t);
  const bool unpaired = (i == 12) || (u == t);
  const int idxT = (t < 288) ? t : 575 - t;  const bool cfT = (t >= 288);
  const int idxU = (u < 288) ? u : 575 - u;  const bool cfU = (u >= 288);
  __shared__ float Xs[4][2][64];
  const int o = lane & 31, half = lane >> 5;
  #pragma unroll
  for(int m = 0; m < 2; ++m){
    int idx = m ? idxU : idxT;
    int rrow = half ? 288 + idx : idx;
    float s = 0.f;
    #pragma unroll
    for(int ks = 0; ks < 8; ++ks)
      s += xp[((size_t)(ks * NB + b) * 576 + rrow) * 32 + o];
    Xs[w][m][half * 32 + o] = s;
  }
  __syncthreads();
  float Fr[2], Fi[2];
  #pragma unroll
  for(int m = 0; m < 2; ++m){
    int idx = m ? idxU : idxT;
    int p2 = idx / 12, qq = idx - p2 * 12;
    int sel = (p2 < 12) ? 0 : 1;
    int pq = (p2 % 12) * 12 + qq;
    const float2* wb = wt + ((size_t)((layer * 2 + sel) * 144 + pq)) * 1024;
    int i0 = half * 16;
    float fr = 0.f, fi = 0.f;
    #pragma unroll
    for(int ii = 0; ii < 16; ++ii){
      int i2 = i0 + ii;
      float xr = Xs[w][m][i2], xi = Xs[w][m][32 + i2];
      float2 wv = wb[i2 * 32 + o];
      fr += xr * wv.x - xi * wv.y;
      fi += xr * wv.y + xi * wv.x;
    }
    fr += __shfl_down(fr, 32);
    fi += __shfl_down(fi, 32);
    Fr[m] = fr; Fi[m] = fi;       // valid in lanes 0..31
  }
  const int c = lane & 31;
  const int srcT = cfT ? 31 - c : c;
  const int srcU = cfU ? 31 - c : c;
  float fax = __shfl(Fr[0], srcT);
  float fay = __shfl(Fi[0], srcT);
  float fbx = __shfl(Fr[1], srcU);
  float fby = __shfl(Fi[1], srcU);
  if(lane < 32){
    float gr = fax;
    float gi = cfT ? -fay : fay;
    if(!unpaired){
      gr += fbx;
      gi -= (cfU ? -fby : fby);
    }
    unsigned short hr = f2b(gr); float lr = gr - b2f(hr);
    unsigned short hi2 = f2b(gi); float li = gi - b2f(hi2);
    size_t base = (size_t)(b * CH + c) * 576;
    ghi[base + k] = hr;          ghi[base + 288 + k] = hi2;
    glo[base + k] = f2b(lr);     glo[base + 288 + k] = f2b(li);
  }
}

// ---------- inverse transform + fused 1x1 conv (+gelu | +fc1/fc2 epilogue) ----------
// block = 512 threads, 128 points, all 32 channels. G (hi+lo) staged in LDS once;
// hot loop: 1 contiguous VTF stream load + 4 ds_read_b128 + 4 MFMA. grid 256 = 1 block/CU.
template<int LAST>
__global__ __launch_bounds__(512, 2) void k_inv(const ushort_t* __restrict__ VTF,
    const ushort_t* __restrict__ ghi, const ushort_t* __restrict__ glo,
    const float* __restrict__ hfull, const float* __restrict__ cw,
    const float* __restrict__ cbias, float* __restrict__ hout,
    ushort_t* __restrict__ houtb, int layer,
    const float* __restrict__ w1, const float* __restrict__ b1,
    const float* __restrict__ w2, const float* __restrict__ b2,
    float* __restrict__ out)
{
  __shared__ ushort_t GH[32][584];   // stride 584 shorts: 2-way-max LDS aliasing
  __shared__ ushort_t GL[32][584];
  __shared__ float hTc[32][129];     // conv input tile [ch][pt 0..127]
  __shared__ float Wl[1024];         // transposed conv W: Wl[i*32+o]
  __shared__ float Bl[32];
  const int tid = threadIdx.x;
  const int b = blockIdx.y;
  const int n0 = blockIdx.x * 128;
  // stage G (coalesced: 32 ch x 576 shorts, hi and lo)
  for(int idx = tid; idx < 2304; idx += 512){
    int ch = idx / 72, g8 = (idx - ch * 72) * 8;
    size_t src = (size_t)(b * CH + ch) * 576 + g8;
    *(short8*)&GH[ch][g8] = *(const short8*)(ghi + src);
    *(short8*)&GL[ch][g8] = *(const short8*)(glo + src);
  }
  // stage conv h tile
  {
    int ch = tid >> 4, grp = tid & 15;
    const float* src = hfull + (size_t)(b * CH + ch) * NN + n0 + grp * 8;
    float4 v0 = *(const float4*)src;
    float4 v1 = *(const float4*)(src + 4);
    int p = grp * 8;
    hTc[ch][p + 0] = v0.x; hTc[ch][p + 1] = v0.y;
    hTc[ch][p + 2] = v0.z; hTc[ch][p + 3] = v0.w;
    hTc[ch][p + 4] = v1.x; hTc[ch][p + 5] = v1.y;
    hTc[ch][p + 6] = v1.z; hTc[ch][p + 7] = v1.w;
  }
  for(int idx = tid; idx < 1024; idx += 512)
    Wl[(idx & 31) * 32 + (idx >> 5)] = cw[layer * 1024 + idx];
  if(tid < 32) Bl[tid] = cbias[layer * 32 + tid];
  __syncthreads();
  const int lane = tid & 63;
  const int w = tid >> 6;            // 8 waves, one n16-tile each
  const int row = lane & 15;
  const int q = lane >> 4;
  const int nloc = w * 16 + row;
  const int n = n0 + nloc;
  const int n16 = blockIdx.x * 8 + w;
  const ushort_t* vb = VTF + ((size_t)(b * 512 + n16) * 18) * 512 + (q * 16 + row) * 8;
  const int ko = q * 8;
  floatx4 acc0 = {0.f,0.f,0.f,0.f}, acc1 = {0.f,0.f,0.f,0.f};
  #pragma unroll
  for(int kk = 0; kk < 18; ++kk){
    short8 Bv  = *(const short8*)(vb + (size_t)kk * 512);
    short8 Ah0 = *(const short8*)&GH[row][ko + kk * 32];
    short8 Al0 = *(const short8*)&GL[row][ko + kk * 32];
    short8 Ah1 = *(const short8*)&GH[16 + row][ko + kk * 32];
    short8 Al1 = *(const short8*)&GL[16 + row][ko + kk * 32];
    acc0 = __builtin_amdgcn_mfma_f32_16x16x32_bf16(Ah0, Bv, acc0, 0, 0, 0);
    acc0 = __builtin_amdgcn_mfma_f32_16x16x32_bf16(Al0, Bv, acc0, 0, 0, 0);
    acc1 = __builtin_amdgcn_mfma_f32_16x16x32_bf16(Ah1, Bv, acc1, 0, 0, 0);
    acc1 = __builtin_amdgcn_mfma_f32_16x16x32_bf16(Al1, Bv, acc1, 0, 0, 0);
  }
  // conv path from LDS (fp32, same summation order -> bitwise identical)
  float acc2[8];
  {
    const int c0 = q * 4;
    #pragma unroll
    for(int r = 0; r < 4; ++r){ acc2[r] = Bl[c0 + r]; acc2[4 + r] = Bl[16 + c0 + r]; }
    #pragma unroll
    for(int i = 0; i < CH; ++i){
      float hv = hTc[i][nloc];
      float4 wv0 = *(const float4*)&Wl[i * 32 + c0];
      float4 wv1 = *(const float4*)&Wl[i * 32 + 16 + c0];
      acc2[0] = fmaf(hv, wv0.x, acc2[0]);
      acc2[1] = fmaf(hv, wv0.y, acc2[1]);
      acc2[2] = fmaf(hv, wv0.z, acc2[2]);
      acc2[3] = fmaf(hv, wv0.w, acc2[3]);
      acc2[4] = fmaf(hv, wv1.x, acc2[4]);
      acc2[5] = fmaf(hv, wv1.y, acc2[5]);
      acc2[6] = fmaf(hv, wv1.z, acc2[6]);
      acc2[7] = fmaf(hv, wv1.w, acc2[7]);
    }
  }
  const float sc = 2.0f / 8192.0f;
  if constexpr(!LAST){
    #pragma unroll
    for(int r = 0; r < 4; ++r){
      int c = q * 4 + r;
      float v0 = gelu_f(acc0[r] * sc + acc2[r]);
      size_t idx0 = (size_t)(b * CH + c) * NN + n;
      hout[idx0] = v0; houtb[idx0] = f2b(v0);
      float v1 = gelu_f(acc1[r] * sc + acc2[4 + r]);
      size_t idx1 = (size_t)(b * CH + 16 + c) * NN + n;
      hout[idx1] = v1; houtb[idx1] = f2b(v1);
    }
  } else {
    __shared__ float hT2[128][33];
    __shared__ float Wfc1[4096];
    __shared__ float b1s[128], w2s[128];
    __shared__ float red2[512];
    #pragma unroll
    for(int r = 0; r < 4; ++r){
      int c = q * 4 + r;
      hT2[nloc][c]      = acc0[r] * sc + acc2[r];
      hT2[nloc][16 + c] = acc1[r] * sc + acc2[4 + r];
    }
    for(int idx2 = tid; idx2 < 4096; idx2 += 512) Wfc1[idx2] = w1[idx2];
    if(tid < 128){ b1s[tid] = b1[tid]; w2s[tid] = w2[tid]; }
    __syncthreads();
    const int nl2 = tid & 127;
    const int js = tid >> 7;            // 4 groups of 32 j
    float acc3 = 0.f;
    for(int jj = js * 32; jj < js * 32 + 32; ++jj){
      float s = b1s[jj];
      #pragma unroll
      for(int i = 0; i < CH; ++i) s = fmaf(hT2[nl2][i], Wfc1[i * 128 + jj], s);
      acc3 = fmaf(gelu_f(s), w2s[jj], acc3);
    }
    red2[tid] = acc3;
    __syncthreads();
    if(js == 0){
      float v = red2[nl2] + red2[nl2 + 128] + red2[nl2 + 256] + red2[nl2 + 384] + b2[0];
      out[(size_t)b * NN + n0 + nl2] = v;
    }
  }
}

// ---------- launch ----------
extern "C" void kernel_launch(void* const* d_in, const int* in_sizes, int n_in,
                              void* d_out, int out_size, void* d_ws, size_t ws_size,
                              hipStream_t stream)
{
  const float* x      = (const float*)d_in[0];
  const float* fc0_w  = (const float*)d_in[1];
  const float* fc0_b  = (const float*)d_in[2];
  const float* spec_w = (const float*)d_in[3];
  const float* conv_w = (const float*)d_in[4];
  const float* conv_b = (const float*)d_in[5];
  const float* fc1_w  = (const float*)d_in[6];
  const float* fc1_b  = (const float*)d_in[7];
  const float* fc2_w  = (const float*)d_in[8];
  const float* fc2_b  = (const float*)d_in[9];
  float* out = (float*)d_out;

  char* w = (char*)d_ws;
  const size_t OFF_PMM  = 0;
  const size_t OFF_WT   = 4096;
  const size_t OFF_AF   = OFF_WT  + 9437184;
  const size_t OFF_VTF  = OFF_AF  + 37748736;
  const size_t OFF_H0   = OFF_VTF + 37748736;
  const size_t OFF_H1   = OFF_H0  + 4194304;
  const size_t OFF_H0B  = OFF_H1  + 4194304;
  const size_t OFF_H1B  = OFF_H0B + 2097152;
  const size_t OFF_XP   = OFF_H1B + 2097152;
  const size_t OFF_GHI  = OFF_XP  + 2359296;
  const size_t OFF_GLO  = OFF_GHI + 147456;

  float4* pmm    = (float4*)(w + OFF_PMM);
  float2* wt     = (float2*)(w + OFF_WT);
  ushort_t* AF   = (ushort_t*)(w + OFF_AF);
  ushort_t* VTF  = (ushort_t*)(w + OFF_VTF);
  float* hbuf[2]     = { (float*)(w + OFF_H0), (float*)(w + OFF_H1) };
  ushort_t* hbufb[2] = { (ushort_t*)(w + OFF_H0B), (ushort_t*)(w + OFF_H1B) };
  float* xp      = (float*)(w + OFF_XP);
  ushort_t* ghi  = (ushort_t*)(w + OFF_GHI);
  ushort_t* glo  = (ushort_t*)(w + OFF_GLO);

  hipLaunchKernelGGL(k_pre, dim3(4736), dim3(256), 0, stream, spec_w, wt, x, pmm);
  hipLaunchKernelGGL(k_vbuild, dim3(1024), dim3(256), 0, stream, x, pmm,
                     fc0_w, fc0_b, AF, VTF, hbuf[0], hbufb[0]);

  for(int l = 0; l < 4; ++l){
    int in = l & 1, outb = 1 - in;
    hipLaunchKernelGGL(k_fwd, dim3(18, 8, NB), dim3(256), 0, stream, AF, hbufb[in], xp);
    hipLaunchKernelGGL(k_mixg, dim3(72, NB), dim3(256), 0, stream, xp, wt, ghi, glo, l);
    if(l < 3)
      hipLaunchKernelGGL(k_inv<0>, dim3(64, NB), dim3(512), 0, stream, VTF, ghi, glo,
                         hbuf[in], conv_w, conv_b, hbuf[outb], hbufb[outb], l,
                         fc1_w, fc1_b, fc2_w, fc2_b, out);
    else
      hipLaunchKernelGGL(k_inv<1>, dim3(64, NB), dim3(512), 0, stream, VTF, ghi, glo,
                         hbuf[in], conv_w, conv_b, hbuf[outb], hbufb[outb], l,
                         fc1_w, fc1_b, fc2_w, fc2_b, out);
  }
  (void)in_sizes; (void)n_in; (void)out_size; (void)ws_size;
}